// Round 2
// baseline (4530.094 us; speedup 1.0000x reference)
//
#include <hip/hip_runtime.h>
#include <hip/hip_bf16.h>

#define NLAYER 6
#define DMODEL 512
#define FFDIM 2048
#define BATCH 16
#define SEQ 2048
#define MROWS (BATCH*SEQ)   // 32768

typedef __hip_bfloat16 bf16;
typedef __attribute__((ext_vector_type(4))) float f32x4;
typedef __attribute__((ext_vector_type(8))) short s16x8;

__device__ __forceinline__ void gload_lds16(const void* g, void* l) {
  __builtin_amdgcn_global_load_lds(
      (const __attribute__((address_space(1))) void*)g,
      (__attribute__((address_space(3))) void*)l, 16, 0, 0);
}

// ---------------- setup kernels ----------------
__global__ void x_init_k(const float* __restrict__ in, float* __restrict__ xo,
                         bf16* __restrict__ xb, size_t n) {
  for (size_t i = (size_t)blockIdx.x * blockDim.x + threadIdx.x; i < n;
       i += (size_t)gridDim.x * blockDim.x) {
    float v = in[i];
    xo[i] = v;
    xb[i] = __float2bfloat16(v);
  }
}

__global__ void cvt_k(const float* __restrict__ in, bf16* __restrict__ out, size_t n) {
  for (size_t i = (size_t)blockIdx.x * blockDim.x + threadIdx.x; i < n;
       i += (size_t)gridDim.x * blockDim.x)
    out[i] = __float2bfloat16(in[i]);
}

// layer slice of w_qkv: [3][512][512][3] (j,o,i,t) f32 -> dest [t][j][o][i] bf16
__global__ void repack_qkv_layer_k(const float* __restrict__ w, bf16* __restrict__ o) {
  int idx = blockIdx.x * blockDim.x + threadIdx.x;   // 9*512*512 total
  int ii = idx & 511;
  int r  = idx >> 9;
  int oo = r & 511; r >>= 9;
  int j  = r % 3;
  int t  = r / 3;
  size_t src = (((size_t)j * 512 + oo) * 512 + ii) * 3 + t;
  o[idx] = __float2bfloat16(w[src]);
}

// layer slice of w_out: [512][512][3] (o,i,t) f32 -> dest [t][o][i] bf16
__global__ void repack_out_layer_k(const float* __restrict__ w, bf16* __restrict__ o) {
  int idx = blockIdx.x * blockDim.x + threadIdx.x;   // 3*512*512 total
  int ii = idx & 511;
  int r  = idx >> 9;
  int oo = r & 511;
  int t  = r >> 9;
  size_t src = ((size_t)oo * 512 + ii) * 3 + t;
  o[idx] = __float2bfloat16(w[src]);
}

// ---------------- GEMM: C[M,N] = sum_t A_shift(t)[M,K] * W_t[N,K] ----------------
enum { E_SIG = 0, E_BIAS = 1, E_OUT = 2, E_RELU = 3, E_FF2 = 4 };

template<int TAPS, int EPI>
__global__ __launch_bounds__(256)
void gemm_k(const bf16* __restrict__ A, const bf16* __restrict__ W,
            const float* __restrict__ bias,
            bf16* __restrict__ Cb, float* Cf,
            const bf16* __restrict__ gate, const int* __restrict__ mask,
            const float* xres, const bf16* __restrict__ zbuf,
            int M, int N, int K)
{
  __shared__ bf16 As[128 * 32];
  __shared__ bf16 Ws[128 * 32];
  const int tid  = threadIdx.x;
  const int lane = tid & 63;
  const int w    = tid >> 6;
  const int wr   = w >> 1, wc = w & 1;
  const int row0 = blockIdx.y * 128;
  const int n0   = blockIdx.x * 128;

  f32x4 acc[4][4] = {};

  const int fr = lane & 15;
  const int ko = (lane >> 4) * 8;

  for (int t = 0; t < TAPS; ++t) {
    const bf16* Wt = W + (size_t)t * N * K;
    const int shift = (TAPS == 3) ? (t - 1) : 0;
    for (int kt = 0; kt < K; kt += 32) {
#pragma unroll
      for (int q = 0; q < 2; ++q) {
        int chunk = w * 2 + q;              // wave-uniform
        int e = chunk * 512 + lane * 8;     // element within 128x32 tile
        int r = e >> 5, c = e & 31;
        // A (with conv shift, zero-pad at sequence boundaries)
        int gr = row0 + r;
        int l  = gr & (SEQ - 1);
        const bf16* srcA;
        int ls = l + shift;
        if ((unsigned)ls < (unsigned)SEQ)
          srcA = A + (size_t)(gr + shift) * K + kt + c;
        else
          srcA = zbuf;
        gload_lds16(srcA, &As[chunk * 512]);
        // W
        const bf16* srcW = Wt + (size_t)(n0 + r) * K + kt + c;
        gload_lds16(srcW, &Ws[chunk * 512]);
      }
      __syncthreads();
      s16x8 af[4], bfr[4];
#pragma unroll
      for (int mi = 0; mi < 4; ++mi)
        af[mi] = *(const s16x8*)&As[(wr * 64 + mi * 16 + fr) * 32 + ko];
#pragma unroll
      for (int ni = 0; ni < 4; ++ni)
        bfr[ni] = *(const s16x8*)&Ws[(wc * 64 + ni * 16 + fr) * 32 + ko];
#pragma unroll
      for (int mi = 0; mi < 4; ++mi)
#pragma unroll
        for (int ni = 0; ni < 4; ++ni)
          acc[mi][ni] = __builtin_amdgcn_mfma_f32_16x16x32_bf16(
              af[mi], bfr[ni], acc[mi][ni], 0, 0, 0);
      __syncthreads();
    }
  }

  // epilogue: C/D layout col=lane&15, row=(lane>>4)*4+j (m89-verified)
#pragma unroll
  for (int mi = 0; mi < 4; ++mi) {
    int rowb = row0 + wr * 64 + mi * 16 + (lane >> 4) * 4;
#pragma unroll
    for (int ni = 0; ni < 4; ++ni) {
      int col = n0 + wc * 64 + ni * 16 + (lane & 15);
      float bval = bias[col];
#pragma unroll
      for (int j = 0; j < 4; ++j) {
        int rr = rowb + j;
        float v = acc[mi][ni][j] + bval;
        size_t idx = (size_t)rr * N + col;
        if (EPI == E_SIG) {
          Cb[idx] = __float2bfloat16(1.f / (1.f + __expf(-v)));
        } else if (EPI == E_BIAS) {
          Cb[idx] = __float2bfloat16(v);
        } else if (EPI == E_RELU) {
          Cb[idx] = __float2bfloat16(fmaxf(v, 0.f));
        } else if (EPI == E_OUT) {
          float gf = __bfloat162float(gate[idx]);
          float mf = (float)mask[rr];
          Cf[idx] = xres[idx] + v * gf * mf;   // in-place: xres == Cf, same idx, same thread
        } else if (EPI == E_FF2) {
          float mf = (float)mask[rr];
          Cf[idx] = xres[idx] + v * mf;        // in-place
        }
      }
    }
  }
}

// ---------------- column max over L (two stage) ----------------
__global__ void colmax_partial_k(const bf16* __restrict__ k, const bf16* __restrict__ v,
                                 float* __restrict__ pk, float* __restrict__ pv) {
  int b  = blockIdx.x >> 1;
  int d  = ((blockIdx.x & 1) << 8) + threadIdx.x;
  int lc = blockIdx.y;
  const int CH = SEQ / 16;
  size_t base = ((size_t)b * SEQ + (size_t)lc * CH) * 1536 + d;
  float mk = -1e30f, mv = -1e30f;
  for (int l = 0; l < CH; ++l) {
    mk = fmaxf(mk, __bfloat162float(k[base]));
    mv = fmaxf(mv, __bfloat162float(v[base]));
    base += 1536;
  }
  size_t pidx = ((size_t)lc * BATCH + b) * DMODEL + d;
  pk[pidx] = mk; pv[pidx] = mv;
}

__global__ void colmax_final_k(const float* __restrict__ pk, const float* __restrict__ pv,
                               float* __restrict__ kg, float* __restrict__ vg) {
  int b = blockIdx.x >> 1;
  int d = ((blockIdx.x & 1) << 8) + threadIdx.x;
  float mk = -1e30f, mv = -1e30f;
  for (int lc = 0; lc < 16; ++lc) {
    size_t pidx = ((size_t)lc * BATCH + b) * DMODEL + d;
    mk = fmaxf(mk, pk[pidx]);
    mv = fmaxf(mv, pv[pidx]);
  }
  kg[(size_t)b * DMODEL + d] = mk;
  vg[(size_t)b * DMODEL + d] = mv;
}

// ---------------- 2-way softmax attention (wave per token) ----------------
__global__ void attn_k(const bf16* __restrict__ qkv, const float* __restrict__ kg,
                       const float* __restrict__ vg, bf16* __restrict__ o) {
  int wid = threadIdx.x >> 6, lane = threadIdx.x & 63;
  int m = blockIdx.x * 4 + wid;
  int b = m >> 11;   // SEQ = 2048
  size_t base3 = (size_t)m * 1536;
  size_t baseo = (size_t)m * DMODEL;
  const float scale = 0.04419417382415922f;  // 1/sqrt(512)
#pragma unroll
  for (int h = 0; h < 8; ++h) {
    int d = (h << 6) + lane;
    float qv  = __bfloat162float(qkv[base3 + d]);
    float kv  = __bfloat162float(qkv[base3 + 512 + d]);
    float vv  = __bfloat162float(qkv[base3 + 1024 + d]);
    float kgv = kg[((size_t)b << 9) + d];
    float vgv = vg[((size_t)b << 9) + d];
    float sl = qv * kv, sg = qv * kgv;
#pragma unroll
    for (int off = 32; off; off >>= 1) {
      sl += __shfl_xor(sl, off);
      sg += __shfl_xor(sg, off);
    }
    sl *= scale; sg *= scale;
    float mx = fmaxf(sl, sg);
    float e0 = __expf(sl - mx), e1 = __expf(sg - mx);
    float inv = 1.f / (e0 + e1);
    o[baseo + d] = __float2bfloat16((e0 * vv + e1 * vgv) * inv);
  }
}

// ---------------- residual + LayerNorm (in-place on xo) ----------------
__global__ void ln_k(const float* r, const float* __restrict__ g,
                     const float* __restrict__ b, float* xo,
                     bf16* __restrict__ xb) {
  int row = blockIdx.x;
  int tid = threadIdx.x;
  size_t base = (size_t)row * DMODEL;
  float v0 = r[base + tid], v1 = r[base + tid + 256];
  float s = v0 + v1, ss = v0 * v0 + v1 * v1;
#pragma unroll
  for (int off = 32; off; off >>= 1) {
    s  += __shfl_xor(s, off);
    ss += __shfl_xor(ss, off);
  }
  __shared__ float sbuf[8];
  int w = tid >> 6, lane = tid & 63;
  if (lane == 0) { sbuf[w] = s; sbuf[4 + w] = ss; }
  __syncthreads();
  if (tid == 0) {
    float st  = sbuf[0] + sbuf[1] + sbuf[2] + sbuf[3];
    float sst = sbuf[4] + sbuf[5] + sbuf[6] + sbuf[7];
    float mean = st / (float)DMODEL;
    float var  = sst / (float)DMODEL - mean * mean;
    sbuf[0] = mean;
    sbuf[1] = rsqrtf(var + 1e-5f);
  }
  __syncthreads();
  float mean = sbuf[0], inv = sbuf[1];
  float y0 = (v0 - mean) * inv * g[tid] + b[tid];
  float y1 = (v1 - mean) * inv * g[tid + 256] + b[tid + 256];
  xo[base + tid] = y0;
  xo[base + tid + 256] = y1;
  xb[base + tid] = __float2bfloat16(y0);
  xb[base + tid + 256] = __float2bfloat16(y1);
}

// ---------------- launch ----------------
extern "C" void kernel_launch(void* const* d_in, const int* in_sizes, int n_in,
                              void* d_out, int out_size, void* d_ws, size_t ws_size,
                              hipStream_t stream) {
  (void)in_sizes; (void)n_in; (void)out_size;
  const float* x      = (const float*)d_in[0];
  const int*   xmask  = (const int*)d_in[1];
  const float* w_qkv  = (const float*)d_in[2];
  const float* b_qkv  = (const float*)d_in[3];
  const float* w_gate = (const float*)d_in[4];
  const float* b_gate = (const float*)d_in[5];
  const float* w_out  = (const float*)d_in[6];
  const float* b_out  = (const float*)d_in[7];
  const float* ln1_g  = (const float*)d_in[8];
  const float* ln1_b  = (const float*)d_in[9];
  const float* w_ff1  = (const float*)d_in[10];
  const float* b_ff1  = (const float*)d_in[11];
  const float* w_ff2  = (const float*)d_in[12];
  const float* b_ff2  = (const float*)d_in[13];
  const float* ln2_g  = (const float*)d_in[14];
  const float* ln2_b  = (const float*)d_in[15];
  float* xo = (float*)d_out;

  char* ws = (char*)d_ws;
  size_t off = 0;
  auto alloc = [&](size_t bytes) {
    char* p = ws + off;
    off += (bytes + 255) & ~(size_t)255;
    return p;
  };
  // xb: bf16 copy of x (always live)
  bf16* xb = (bf16*)alloc((size_t)MROWS * DMODEL * 2);
  // shared region: [qkvb | gateb] during attention phase, hb during FFN phase
  char* R2 = alloc((size_t)MROWS * FFDIM * 2);              // 134,217,728 B
  bf16* qkvb  = (bf16*)R2;                                  // 100,663,296 B
  bf16* gateb = (bf16*)(R2 + (size_t)MROWS * 1536 * 2);     //  33,554,432 B
  bf16* hb    = (bf16*)R2;                                  // 134,217,728 B (FFN phase)
  bf16* ob    = (bf16*)alloc((size_t)MROWS * DMODEL * 2);
  float* kg   = (float*)alloc((size_t)BATCH * DMODEL * 4);
  float* vg   = (float*)alloc((size_t)BATCH * DMODEL * 4);
  float* pk   = (float*)alloc((size_t)16 * BATCH * DMODEL * 4);
  float* pv   = (float*)alloc((size_t)16 * BATCH * DMODEL * 4);
  bf16* zbuf  = (bf16*)alloc(256);
  // per-layer repacked weights (overwritten each layer)
  bf16* wq  = (bf16*)alloc((size_t)9 * DMODEL * DMODEL * 2);
  bf16* wg  = (bf16*)alloc((size_t)DMODEL * DMODEL * 2);
  bf16* wo  = (bf16*)alloc((size_t)3 * DMODEL * DMODEL * 2);
  bf16* wf1 = (bf16*)alloc((size_t)FFDIM * DMODEL * 2);
  bf16* wf2 = (bf16*)alloc((size_t)DMODEL * FFDIM * 2);

  // tripwire: if ws is too small, do nothing -> clean absmax fail (not a crash)
  if (off > ws_size) return;

  hipMemsetAsync(zbuf, 0, 256, stream);
  x_init_k<<<2048, 256, 0, stream>>>(x, xo, xb, (size_t)MROWS * DMODEL);

  dim3 gN512(512 / 128, MROWS / 128);    // (4, 256)
  dim3 gN1536(1536 / 128, MROWS / 128);  // (12, 256)
  dim3 gN2048(2048 / 128, MROWS / 128);  // (16, 256)

  for (int i = 0; i < NLAYER; ++i) {
    // repack this layer's weights to bf16 [N][K] per tap
    cvt_k<<<1024, 256, 0, stream>>>(w_gate + (size_t)i * DMODEL * DMODEL, wg,
                                    (size_t)DMODEL * DMODEL);
    repack_qkv_layer_k<<<9216, 256, 0, stream>>>(
        w_qkv + (size_t)i * 3 * DMODEL * DMODEL * 3, wq);
    repack_out_layer_k<<<3072, 256, 0, stream>>>(
        w_out + (size_t)i * DMODEL * DMODEL * 3, wo);
    cvt_k<<<4096, 256, 0, stream>>>(w_ff1 + (size_t)i * FFDIM * DMODEL, wf1,
                                    (size_t)FFDIM * DMODEL);
    cvt_k<<<4096, 256, 0, stream>>>(w_ff2 + (size_t)i * DMODEL * FFDIM, wf2,
                                    (size_t)DMODEL * FFDIM);

    // gate = sigmoid(x @ w_gate^T + b_gate)
    gemm_k<1, E_SIG><<<gN512, 256, 0, stream>>>(
        xb, wg, b_gate + (size_t)i * DMODEL, gateb, nullptr,
        nullptr, nullptr, nullptr, zbuf, MROWS, DMODEL, DMODEL);
    // qkv = conv1d3(x) fused over q/k/v, N = 1536
    gemm_k<3, E_BIAS><<<gN1536, 256, 0, stream>>>(
        xb, wq, b_qkv + (size_t)i * 3 * DMODEL, qkvb, nullptr,
        nullptr, nullptr, nullptr, zbuf, MROWS, 1536, DMODEL);
    // k_g, v_g global max over L
    colmax_partial_k<<<dim3(32, 16), 256, 0, stream>>>(qkvb + 512, qkvb + 1024, pk, pv);
    colmax_final_k<<<32, 256, 0, stream>>>(pk, pv, kg, vg);
    // 2-way softmax attention
    attn_k<<<MROWS / 4, 256, 0, stream>>>(qkvb, kg, vg, ob);
    // xo = xo + conv1d3(o) * gate * mask   (in-place residual)
    gemm_k<3, E_OUT><<<gN512, 256, 0, stream>>>(
        ob, wo, b_out + (size_t)i * DMODEL, nullptr, xo,
        gateb, xmask, xo, zbuf, MROWS, DMODEL, DMODEL);
    // x = LN(xo)  (in-place)
    ln_k<<<MROWS, 256, 0, stream>>>(xo, ln1_g + (size_t)i * DMODEL,
                                    ln1_b + (size_t)i * DMODEL, xo, xb);
    // h = relu(x @ w_ff1^T + b_ff1)
    gemm_k<1, E_RELU><<<gN2048, 256, 0, stream>>>(
        xb, wf1, b_ff1 + (size_t)i * FFDIM, hb, nullptr,
        nullptr, nullptr, nullptr, zbuf, MROWS, FFDIM, DMODEL);
    // xo = xo + (h @ w_ff2^T + b_ff2) * mask   (in-place residual)
    gemm_k<1, E_FF2><<<gN512, 256, 0, stream>>>(
        hb, wf2, b_ff2 + (size_t)i * DMODEL, nullptr, xo,
        nullptr, xmask, xo, zbuf, MROWS, DMODEL, FFDIM);
    // x = LN(xo)  (in-place)
    ln_k<<<MROWS, 256, 0, stream>>>(xo, ln2_g + (size_t)i * DMODEL,
                                    ln2_b + (size_t)i * DMODEL, xo, xb);
  }
}

// Round 3
// 3923.582 us; speedup vs baseline: 1.1546x; 1.1546x over previous
//
#include <hip/hip_runtime.h>
#include <hip/hip_bf16.h>

#define NLAYER 6
#define DMODEL 512
#define FFDIM 2048
#define BATCH 16
#define SEQ 2048
#define MROWS (BATCH*SEQ)   // 32768

typedef __hip_bfloat16 bf16;
typedef __attribute__((ext_vector_type(4))) float f32x4;
typedef __attribute__((ext_vector_type(8))) short s16x8;

__device__ __forceinline__ void gload_lds16(const void* g, void* l) {
  __builtin_amdgcn_global_load_lds(
      (const __attribute__((address_space(1))) void*)g,
      (__attribute__((address_space(3))) void*)l, 16, 0, 0);
}

// ---------------- setup kernels ----------------
__global__ void x_init_k(const float* __restrict__ in, float* __restrict__ xo,
                         bf16* __restrict__ xb, size_t n) {
  for (size_t i = (size_t)blockIdx.x * blockDim.x + threadIdx.x; i < n;
       i += (size_t)gridDim.x * blockDim.x) {
    float v = in[i];
    xo[i] = v;
    xb[i] = __float2bfloat16(v);
  }
}

__global__ void cvt_k(const float* __restrict__ in, bf16* __restrict__ out, size_t n) {
  for (size_t i = (size_t)blockIdx.x * blockDim.x + threadIdx.x; i < n;
       i += (size_t)gridDim.x * blockDim.x)
    out[i] = __float2bfloat16(in[i]);
}

// layer slice of w_qkv: [3][512][512][3] (j,o,i,t) f32 -> dest [t][j][o][i] bf16
__global__ void repack_qkv_layer_k(const float* __restrict__ w, bf16* __restrict__ o) {
  int idx = blockIdx.x * blockDim.x + threadIdx.x;   // 9*512*512 total
  int ii = idx & 511;
  int r  = idx >> 9;
  int oo = r & 511; r >>= 9;
  int j  = r % 3;
  int t  = r / 3;
  size_t src = (((size_t)j * 512 + oo) * 512 + ii) * 3 + t;
  o[idx] = __float2bfloat16(w[src]);
}

// layer slice of w_out: [512][512][3] (o,i,t) f32 -> dest [t][o][i] bf16
__global__ void repack_out_layer_k(const float* __restrict__ w, bf16* __restrict__ o) {
  int idx = blockIdx.x * blockDim.x + threadIdx.x;   // 3*512*512 total
  int ii = idx & 511;
  int r  = idx >> 9;
  int oo = r & 511;
  int t  = r >> 9;
  size_t src = ((size_t)oo * 512 + ii) * 3 + t;
  o[idx] = __float2bfloat16(w[src]);
}

// ---------------- GEMM: C[M,N] = sum_t A_shift(t)[M,K] * W_t[N,K] ----------------
// BM=256, BN=128, BK=64, 8 waves (4M x 2N), 3-deep LDS pipeline, counted vmcnt,
// T2 XOR swizzle (pre-swizzled global source + swizzled ds_read), T5 setprio,
// T1 bijective XCD swizzle.
enum { E_SIG = 0, E_BIAS = 1, E_OUT = 2, E_RELU = 3, E_FF2 = 4 };

#define ATILE 16384   // 256*64 bf16 elements
#define BUFE  24576   // (256+128)*64 elements per buffer

template<int TAPS, int EPI, int KK>
__global__ __launch_bounds__(512, 2)
void gemm_k(const bf16* __restrict__ A, const bf16* __restrict__ W,
            const float* __restrict__ bias,
            bf16* __restrict__ Cb, float* Cf,
            const bf16* __restrict__ gate, const int* __restrict__ mask,
            const float* xres, const bf16* __restrict__ zbuf,
            int M, int N)
{
  constexpr int KT = KK / 64;        // K-tiles per tap
  constexpr int NT = TAPS * KT;      // total virtual K-tiles (8, 24, or 32)
  __shared__ bf16 lds[3 * BUFE];     // 147456 B

  const int tid  = threadIdx.x;
  const int lane = tid & 63;
  const int w    = tid >> 6;         // 0..7
  const int wr   = w >> 1;           // 0..3 (M)
  const int wc   = w & 1;            // 0..1 (N)
  const int frow = lane & 15;
  const int kq   = lane >> 4;        // 0..3

  // T1: bijective XCD swizzle (nwg % 8 == 0 for all instantiations)
  const int nwg = gridDim.x * gridDim.y;
  const int wg  = blockIdx.y * gridDim.x + blockIdx.x;
  const int q8  = nwg >> 3;
  const int swz = (wg & 7) * q8 + (wg >> 3);
  const int row0 = (swz / gridDim.x) * 256;
  const int n0   = (swz % gridDim.x) * 128;

  // stage one virtual K-tile v into lds buffer v%3.
  // LDS layout: A rows 0..255 (64 cols), B rows 0..127; within a row the 8
  // 16B-groups are stored with group g holding global group g^(row&7).
  auto stage = [&](int v) {
    int tap, kt;
    if (TAPS == 3) { tap = v / KT; kt = (v - tap * KT) * 64; }
    else           { tap = 0;      kt = v * 64; }
    const int shift = tap - 1;                 // only meaningful for TAPS==3
    const bf16* Wt = W + (size_t)tap * N * KK;
    bf16* dst = lds + (v % 3) * BUFE;
#pragma unroll
    for (int i = 0; i < 4; ++i) {
      int c = tid + i * 512;                   // 0..2047
      int row = c >> 3, g = c & 7;
      int gsw = (g ^ (row & 7)) * 8;           // pre-swizzled source group
      const bf16* src;
      if (TAPS == 3) {
        int grow = row0 + row;
        int ls = (grow & (SEQ - 1)) + shift;
        src = ((unsigned)ls < (unsigned)SEQ)
            ? A + (size_t)(grow + shift) * KK + kt + gsw
            : zbuf;
      } else {
        src = A + (size_t)(row0 + row) * KK + kt + gsw;
      }
      gload_lds16(src, dst + c * 8);
    }
#pragma unroll
    for (int i = 0; i < 2; ++i) {
      int c = tid + i * 512;                   // 0..1023
      int row = c >> 3, g = c & 7;
      int gsw = (g ^ (row & 7)) * 8;
      gload_lds16(Wt + (size_t)(n0 + row) * KK + kt + gsw,
                  dst + ATILE + c * 8);
    }
  };

  f32x4 acc[4][4] = {};

  // prologue: 3 tiles in flight (18 loads/wave)
  stage(0); stage(1); stage(2);

  for (int t = 0; t < NT; ++t) {
    // counted vmcnt: wait own tile-t loads only; keep t+1,t+2 in flight
    if (t < NT - 2)       asm volatile("s_waitcnt vmcnt(12)" ::: "memory");
    else if (t == NT - 2) asm volatile("s_waitcnt vmcnt(6)"  ::: "memory");
    else                  asm volatile("s_waitcnt vmcnt(0)"  ::: "memory");
    __builtin_amdgcn_s_barrier();
    asm volatile("" ::: "memory");

    const bf16* Ab = lds + (t % 3) * BUFE;
    const bf16* Bb = Ab + ATILE;
    s16x8 af[4][2], bg[4][2];
#pragma unroll
    for (int mi = 0; mi < 4; ++mi)
#pragma unroll
      for (int ks = 0; ks < 2; ++ks) {
        int row = wr * 64 + mi * 16 + frow;
        int kg  = ks * 4 + kq;
        af[mi][ks] = *(const s16x8*)&Ab[row * 64 + ((kg ^ (row & 7)) * 8)];
      }
#pragma unroll
    for (int ni = 0; ni < 4; ++ni)
#pragma unroll
      for (int ks = 0; ks < 2; ++ks) {
        int row = wc * 64 + ni * 16 + frow;
        int kg  = ks * 4 + kq;
        bg[ni][ks] = *(const s16x8*)&Bb[row * 64 + ((kg ^ (row & 7)) * 8)];
      }

    __builtin_amdgcn_s_setprio(1);
#pragma unroll
    for (int mi = 0; mi < 4; ++mi)
#pragma unroll
      for (int ni = 0; ni < 4; ++ni) {
        acc[mi][ni] = __builtin_amdgcn_mfma_f32_16x16x32_bf16(
            af[mi][0], bg[ni][0], acc[mi][ni], 0, 0, 0);
        acc[mi][ni] = __builtin_amdgcn_mfma_f32_16x16x32_bf16(
            af[mi][1], bg[ni][1], acc[mi][ni], 0, 0, 0);
      }
    __builtin_amdgcn_s_setprio(0);

    asm volatile("" ::: "memory");
    __builtin_amdgcn_s_barrier();          // all waves done reading buf t%3
    if (t + 3 < NT) stage(t + 3);          // safe to overwrite it now
  }

  // epilogue: C/D layout col=lane&15, row=(lane>>4)*4+j (m89-verified)
#pragma unroll
  for (int mi = 0; mi < 4; ++mi) {
    int rowb = row0 + wr * 64 + mi * 16 + kq * 4;
#pragma unroll
    for (int ni = 0; ni < 4; ++ni) {
      int col = n0 + wc * 64 + ni * 16 + frow;
      float bval = bias[col];
#pragma unroll
      for (int j = 0; j < 4; ++j) {
        int rr = rowb + j;
        float v = acc[mi][ni][j] + bval;
        size_t idx = (size_t)rr * N + col;
        if (EPI == E_SIG) {
          Cb[idx] = __float2bfloat16(1.f / (1.f + __expf(-v)));
        } else if (EPI == E_BIAS) {
          Cb[idx] = __float2bfloat16(v);
        } else if (EPI == E_RELU) {
          Cb[idx] = __float2bfloat16(fmaxf(v, 0.f));
        } else if (EPI == E_OUT) {
          float gf = __bfloat162float(gate[idx]);
          float mf = (float)mask[rr];
          Cf[idx] = xres[idx] + v * gf * mf;   // in-place: xres == Cf, same idx
        } else if (EPI == E_FF2) {
          float mf = (float)mask[rr];
          Cf[idx] = xres[idx] + v * mf;        // in-place
        }
      }
    }
  }
}

// ---------------- column max over L (two stage) ----------------
__global__ void colmax_partial_k(const bf16* __restrict__ k, const bf16* __restrict__ v,
                                 float* __restrict__ pk, float* __restrict__ pv) {
  int b  = blockIdx.x >> 1;
  int d  = ((blockIdx.x & 1) << 8) + threadIdx.x;
  int lc = blockIdx.y;
  const int CH = SEQ / 16;
  size_t base = ((size_t)b * SEQ + (size_t)lc * CH) * 1536 + d;
  float mk = -1e30f, mv = -1e30f;
  for (int l = 0; l < CH; ++l) {
    mk = fmaxf(mk, __bfloat162float(k[base]));
    mv = fmaxf(mv, __bfloat162float(v[base]));
    base += 1536;
  }
  size_t pidx = ((size_t)lc * BATCH + b) * DMODEL + d;
  pk[pidx] = mk; pv[pidx] = mv;
}

__global__ void colmax_final_k(const float* __restrict__ pk, const float* __restrict__ pv,
                               float* __restrict__ kg, float* __restrict__ vg) {
  int b = blockIdx.x >> 1;
  int d = ((blockIdx.x & 1) << 8) + threadIdx.x;
  float mk = -1e30f, mv = -1e30f;
  for (int lc = 0; lc < 16; ++lc) {
    size_t pidx = ((size_t)lc * BATCH + b) * DMODEL + d;
    mk = fmaxf(mk, pk[pidx]);
    mv = fmaxf(mv, pv[pidx]);
  }
  kg[(size_t)b * DMODEL + d] = mk;
  vg[(size_t)b * DMODEL + d] = mv;
}

// ---------------- 2-way softmax attention (wave per token) ----------------
__global__ void attn_k(const bf16* __restrict__ qkv, const float* __restrict__ kg,
                       const float* __restrict__ vg, bf16* __restrict__ o) {
  int wid = threadIdx.x >> 6, lane = threadIdx.x & 63;
  int m = blockIdx.x * 4 + wid;
  int b = m >> 11;   // SEQ = 2048
  size_t base3 = (size_t)m * 1536;
  size_t baseo = (size_t)m * DMODEL;
  const float scale = 0.04419417382415922f;  // 1/sqrt(512)
#pragma unroll
  for (int h = 0; h < 8; ++h) {
    int d = (h << 6) + lane;
    float qv  = __bfloat162float(qkv[base3 + d]);
    float kv  = __bfloat162float(qkv[base3 + 512 + d]);
    float vv  = __bfloat162float(qkv[base3 + 1024 + d]);
    float kgv = kg[((size_t)b << 9) + d];
    float vgv = vg[((size_t)b << 9) + d];
    float sl = qv * kv, sg = qv * kgv;
#pragma unroll
    for (int off = 32; off; off >>= 1) {
      sl += __shfl_xor(sl, off);
      sg += __shfl_xor(sg, off);
    }
    sl *= scale; sg *= scale;
    float mx = fmaxf(sl, sg);
    float e0 = __expf(sl - mx), e1 = __expf(sg - mx);
    float inv = 1.f / (e0 + e1);
    o[baseo + d] = __float2bfloat16((e0 * vv + e1 * vgv) * inv);
  }
}

// ---------------- residual + LayerNorm (in-place on xo) ----------------
__global__ void ln_k(const float* r, const float* __restrict__ g,
                     const float* __restrict__ b, float* xo,
                     bf16* __restrict__ xb) {
  int row = blockIdx.x;
  int tid = threadIdx.x;
  size_t base = (size_t)row * DMODEL;
  float v0 = r[base + tid], v1 = r[base + tid + 256];
  float s = v0 + v1, ss = v0 * v0 + v1 * v1;
#pragma unroll
  for (int off = 32; off; off >>= 1) {
    s  += __shfl_xor(s, off);
    ss += __shfl_xor(ss, off);
  }
  __shared__ float sbuf[8];
  int w = tid >> 6, lane = tid & 63;
  if (lane == 0) { sbuf[w] = s; sbuf[4 + w] = ss; }
  __syncthreads();
  if (tid == 0) {
    float st  = sbuf[0] + sbuf[1] + sbuf[2] + sbuf[3];
    float sst = sbuf[4] + sbuf[5] + sbuf[6] + sbuf[7];
    float mean = st / (float)DMODEL;
    float var  = sst / (float)DMODEL - mean * mean;
    sbuf[0] = mean;
    sbuf[1] = rsqrtf(var + 1e-5f);
  }
  __syncthreads();
  float mean = sbuf[0], inv = sbuf[1];
  float y0 = (v0 - mean) * inv * g[tid] + b[tid];
  float y1 = (v1 - mean) * inv * g[tid + 256] + b[tid + 256];
  xo[base + tid] = y0;
  xo[base + tid + 256] = y1;
  xb[base + tid] = __float2bfloat16(y0);
  xb[base + tid + 256] = __float2bfloat16(y1);
}

// ---------------- launch ----------------
extern "C" void kernel_launch(void* const* d_in, const int* in_sizes, int n_in,
                              void* d_out, int out_size, void* d_ws, size_t ws_size,
                              hipStream_t stream) {
  (void)in_sizes; (void)n_in; (void)out_size;
  const float* x      = (const float*)d_in[0];
  const int*   xmask  = (const int*)d_in[1];
  const float* w_qkv  = (const float*)d_in[2];
  const float* b_qkv  = (const float*)d_in[3];
  const float* w_gate = (const float*)d_in[4];
  const float* b_gate = (const float*)d_in[5];
  const float* w_out  = (const float*)d_in[6];
  const float* b_out  = (const float*)d_in[7];
  const float* ln1_g  = (const float*)d_in[8];
  const float* ln1_b  = (const float*)d_in[9];
  const float* w_ff1  = (const float*)d_in[10];
  const float* b_ff1  = (const float*)d_in[11];
  const float* w_ff2  = (const float*)d_in[12];
  const float* b_ff2  = (const float*)d_in[13];
  const float* ln2_g  = (const float*)d_in[14];
  const float* ln2_b  = (const float*)d_in[15];
  float* xo = (float*)d_out;

  char* ws = (char*)d_ws;
  size_t off = 0;
  auto alloc = [&](size_t bytes) {
    char* p = ws + off;
    off += (bytes + 255) & ~(size_t)255;
    return p;
  };
  // xb: bf16 copy of x (always live)
  bf16* xb = (bf16*)alloc((size_t)MROWS * DMODEL * 2);
  // shared region: [qkvb | gateb] during attention phase, hb during FFN phase
  char* R2 = alloc((size_t)MROWS * FFDIM * 2);              // 134,217,728 B
  bf16* qkvb  = (bf16*)R2;                                  // 100,663,296 B
  bf16* gateb = (bf16*)(R2 + (size_t)MROWS * 1536 * 2);     //  33,554,432 B
  bf16* hb    = (bf16*)R2;                                  // 134,217,728 B (FFN phase)
  bf16* ob    = (bf16*)alloc((size_t)MROWS * DMODEL * 2);
  float* kg   = (float*)alloc((size_t)BATCH * DMODEL * 4);
  float* vg   = (float*)alloc((size_t)BATCH * DMODEL * 4);
  float* pk   = (float*)alloc((size_t)16 * BATCH * DMODEL * 4);
  float* pv   = (float*)alloc((size_t)16 * BATCH * DMODEL * 4);
  bf16* zbuf  = (bf16*)alloc(256);
  // per-layer repacked weights (overwritten each layer)
  bf16* wq  = (bf16*)alloc((size_t)9 * DMODEL * DMODEL * 2);
  bf16* wg  = (bf16*)alloc((size_t)DMODEL * DMODEL * 2);
  bf16* wo  = (bf16*)alloc((size_t)3 * DMODEL * DMODEL * 2);
  bf16* wf1 = (bf16*)alloc((size_t)FFDIM * DMODEL * 2);
  bf16* wf2 = (bf16*)alloc((size_t)DMODEL * FFDIM * 2);

  // tripwire: if ws is too small, do nothing -> clean absmax fail (not a crash)
  if (off > ws_size) return;

  hipMemsetAsync(zbuf, 0, 256, stream);
  x_init_k<<<2048, 256, 0, stream>>>(x, xo, xb, (size_t)MROWS * DMODEL);

  dim3 gN512(512 / 128, MROWS / 256);    // (4, 128)  -> 512 blocks
  dim3 gN1536(1536 / 128, MROWS / 256);  // (12, 128) -> 1536 blocks
  dim3 gN2048(2048 / 128, MROWS / 256);  // (16, 128) -> 2048 blocks

  for (int i = 0; i < NLAYER; ++i) {
    // repack this layer's weights to bf16 [N][K] per tap
    cvt_k<<<1024, 256, 0, stream>>>(w_gate + (size_t)i * DMODEL * DMODEL, wg,
                                    (size_t)DMODEL * DMODEL);
    repack_qkv_layer_k<<<9216, 256, 0, stream>>>(
        w_qkv + (size_t)i * 3 * DMODEL * DMODEL * 3, wq);
    repack_out_layer_k<<<3072, 256, 0, stream>>>(
        w_out + (size_t)i * DMODEL * DMODEL * 3, wo);
    cvt_k<<<4096, 256, 0, stream>>>(w_ff1 + (size_t)i * FFDIM * DMODEL, wf1,
                                    (size_t)FFDIM * DMODEL);
    cvt_k<<<4096, 256, 0, stream>>>(w_ff2 + (size_t)i * DMODEL * FFDIM, wf2,
                                    (size_t)DMODEL * FFDIM);

    // gate = sigmoid(x @ w_gate^T + b_gate)
    gemm_k<1, E_SIG, 512><<<gN512, 512, 0, stream>>>(
        xb, wg, b_gate + (size_t)i * DMODEL, gateb, nullptr,
        nullptr, nullptr, nullptr, zbuf, MROWS, DMODEL);
    // qkv = conv1d3(x) fused over q/k/v, N = 1536
    gemm_k<3, E_BIAS, 512><<<gN1536, 512, 0, stream>>>(
        xb, wq, b_qkv + (size_t)i * 3 * DMODEL, qkvb, nullptr,
        nullptr, nullptr, nullptr, zbuf, MROWS, 1536);
    // k_g, v_g global max over L
    colmax_partial_k<<<dim3(32, 16), 256, 0, stream>>>(qkvb + 512, qkvb + 1024, pk, pv);
    colmax_final_k<<<32, 256, 0, stream>>>(pk, pv, kg, vg);
    // 2-way softmax attention
    attn_k<<<MROWS / 4, 256, 0, stream>>>(qkvb, kg, vg, ob);
    // xo = xo + conv1d3(o) * gate * mask   (in-place residual)
    gemm_k<3, E_OUT, 512><<<gN512, 512, 0, stream>>>(
        ob, wo, b_out + (size_t)i * DMODEL, nullptr, xo,
        gateb, xmask, xo, zbuf, MROWS, DMODEL);
    // x = LN(xo)  (in-place)
    ln_k<<<MROWS, 256, 0, stream>>>(xo, ln1_g + (size_t)i * DMODEL,
                                    ln1_b + (size_t)i * DMODEL, xo, xb);
    // h = relu(x @ w_ff1^T + b_ff1)
    gemm_k<1, E_RELU, 512><<<gN2048, 512, 0, stream>>>(
        xb, wf1, b_ff1 + (size_t)i * FFDIM, hb, nullptr,
        nullptr, nullptr, nullptr, zbuf, MROWS, FFDIM);
    // xo = xo + (h @ w_ff2^T + b_ff2) * mask   (in-place residual)
    gemm_k<1, E_FF2, 2048><<<gN512, 512, 0, stream>>>(
        hb, wf2, b_ff2 + (size_t)i * DMODEL, nullptr, xo,
        nullptr, xmask, xo, zbuf, MROWS, DMODEL);
    // x = LN(xo)  (in-place)
    ln_k<<<MROWS, 256, 0, stream>>>(xo, ln2_g + (size_t)i * DMODEL,
                                    ln2_b + (size_t)i * DMODEL, xo, xb);
  }
}

// Round 4
// 3505.671 us; speedup vs baseline: 1.2922x; 1.1192x over previous
//
#include <hip/hip_runtime.h>
#include <hip/hip_bf16.h>

#define NLAYER 6
#define DMODEL 512
#define FFDIM 2048
#define BATCH 16
#define SEQ 2048
#define MROWS (BATCH*SEQ)   // 32768

typedef __hip_bfloat16 bf16;
typedef __attribute__((ext_vector_type(4))) float f32x4;
typedef __attribute__((ext_vector_type(8))) short s16x8;

__device__ __forceinline__ void gload_lds16(const void* g, void* l) {
  __builtin_amdgcn_global_load_lds(
      (const __attribute__((address_space(1))) void*)g,
      (__attribute__((address_space(3))) void*)l, 16, 0, 0);
}

// ---------------- setup kernels ----------------
__global__ void x_init_k(const float* __restrict__ in, float* __restrict__ xo,
                         bf16* __restrict__ xb, size_t n) {
  for (size_t i = (size_t)blockIdx.x * blockDim.x + threadIdx.x; i < n;
       i += (size_t)gridDim.x * blockDim.x) {
    float v = in[i];
    xo[i] = v;
    xb[i] = __float2bfloat16(v);
  }
}

__global__ void cvt_k(const float* __restrict__ in, bf16* __restrict__ out, size_t n) {
  for (size_t i = (size_t)blockIdx.x * blockDim.x + threadIdx.x; i < n;
       i += (size_t)gridDim.x * blockDim.x)
    out[i] = __float2bfloat16(in[i]);
}

// layer slice of w_qkv: [3][512][512][3] (j,o,i,t) f32 -> dest [t][j][o][i] bf16
__global__ void repack_qkv_layer_k(const float* __restrict__ w, bf16* __restrict__ o) {
  int idx = blockIdx.x * blockDim.x + threadIdx.x;   // 9*512*512 total
  int ii = idx & 511;
  int r  = idx >> 9;
  int oo = r & 511; r >>= 9;
  int j  = r % 3;
  int t  = r / 3;
  size_t src = (((size_t)j * 512 + oo) * 512 + ii) * 3 + t;
  o[idx] = __float2bfloat16(w[src]);
}

// layer slice of w_out: [512][512][3] (o,i,t) f32 -> dest [t][o][i] bf16
__global__ void repack_out_layer_k(const float* __restrict__ w, bf16* __restrict__ o) {
  int idx = blockIdx.x * blockDim.x + threadIdx.x;   // 3*512*512 total
  int ii = idx & 511;
  int r  = idx >> 9;
  int oo = r & 511;
  int t  = r >> 9;
  size_t src = ((size_t)oo * 512 + ii) * 3 + t;
  o[idx] = __float2bfloat16(w[src]);
}

// ---------------- GEMM: C[M,N] = sum_t A_shift(t)[M,K] * W_t[N,K] ----------------
// BM=256, BN=256, BK=64, 8 waves (2M x 4N, per-wave 128x64 output),
// 2 LDS buffers (128 KiB), 3 fine phases per K-tile, pass-aligned staging with
// counted vmcnt (never 0 until last tile), T2 swizzle, T5 setprio, T1 XCD swizzle.
enum { E_SIG = 0, E_BIAS = 1, E_OUT = 2, E_RELU = 3, E_FF2 = 4 };

#define ABUF 16384   // 256*64 bf16 elements (A region)
#define BUFE 32768   // A + B regions per buffer

template<int TAPS, int EPI, int KK>
__global__ __launch_bounds__(512, 2)
void gemm_k(const bf16* __restrict__ A, const bf16* __restrict__ W,
            const float* __restrict__ bias,
            bf16* __restrict__ Cb, float* Cf,
            const bf16* __restrict__ gate, const int* __restrict__ mask,
            const float* xres, const bf16* __restrict__ zbuf,
            int M, int N)
{
  constexpr int KT = KK / 64;        // K-tiles per tap
  constexpr int NT = TAPS * KT;      // virtual K-tiles (8, 24, or 32)
  __shared__ bf16 lds[2 * BUFE];     // 131072 B

  const int tid  = threadIdx.x;
  const int lane = tid & 63;
  const int w    = tid >> 6;         // 0..7
  const int wr   = w >> 2;           // 0..1 (M)
  const int wc   = w & 3;            // 0..3 (N)
  const int frow = lane & 15;
  const int kq   = lane >> 4;        // 0..3

  // T1: bijective XCD swizzle (nwg % 8 == 0 for all instantiations)
  const int nwg = gridDim.x * gridDim.y;
  const int wg  = blockIdx.y * gridDim.x + blockIdx.x;
  const int q8  = nwg >> 3;
  const int swz = (wg & 7) * q8 + (wg >> 3);
  const int row0 = (swz / gridDim.x) * 256;
  const int n0   = (swz % gridDim.x) * 256;

  // ---- staging passes (linear LDS dest, pre-swizzled global source) ----
  // A pass i (i=0..3): rows [i*64, i*64+64)
  auto stageA = [&](int v, int i) {
    int tap, kt;
    if (TAPS == 3) { tap = v / KT; kt = (v - tap * KT) * 64; }
    else           { tap = 0;      kt = v * 64; }
    const int shift = tap - 1;
    int row = i * 64 + (tid >> 3);
    int g   = tid & 7;
    int gsw = (g ^ (row & 7)) * 8;
    bf16* dst = lds + (v & 1) * BUFE + i * 4096 + tid * 8;
    const bf16* src;
    if (TAPS == 3) {
      int grow = row0 + row;
      int ls = (grow & (SEQ - 1)) + shift;
      src = ((unsigned)ls < (unsigned)SEQ)
          ? A + (size_t)(grow + shift) * KK + kt + gsw
          : zbuf;
    } else {
      src = A + (size_t)(row0 + row) * KK + kt + gsw;
    }
    gload_lds16(src, dst);
  };
  // B pass j (j=0..3): rows {base..base+31} U {base+64..base+95},
  // base = (j>>1)*128 + (j&1)*32.  Passes {0,2} = nh0 rows, {1,3} = nh1 rows.
  auto stageB = [&](int v, int j) {
    int tap, kt;
    if (TAPS == 3) { tap = v / KT; kt = (v - tap * KT) * 64; }
    else           { tap = 0;      kt = v * 64; }
    const bf16* Wt = W + (size_t)tap * N * KK;
    int u   = tid >> 3;
    int row = (j >> 1) * 128 + (j & 1) * 32 + (u & 31) + (u >> 5) * 64;
    int g   = tid & 7;
    int gsw = (g ^ (row & 7)) * 8;
    bf16* dst = lds + (v & 1) * BUFE + ABUF + row * 64 + g * 8;
    gload_lds16(Wt + (size_t)(n0 + row) * KK + kt + gsw, dst);
  };

  f32x4 acc[8][4] = {};

  // prologue: tile 0, canonical order (phase-0 set first, then B1,B3, then A1,A3)
  stageA(0, 0); stageA(0, 2); stageB(0, 0); stageB(0, 2);
  stageB(0, 1); stageB(0, 3);
  stageA(0, 1); stageA(0, 3);

  for (int t = 0; t < NT; ++t) {
    const bf16* Ab = lds + (t & 1) * BUFE;
    const bf16* Bb = Ab + ABUF;
    const bool pre = (t + 1 < NT);

    auto ldA = [&](int mi, int ks) -> s16x8 {   // mi 0..7
      int row = wr * 128 + mi * 16 + frow;
      int kg  = ks * 4 + kq;
      return *(const s16x8*)&Ab[row * 64 + ((kg ^ (row & 7)) * 8)];
    };
    auto ldB = [&](int nj, int ks) -> s16x8 {   // nj 0..3
      int row = wc * 64 + nj * 16 + frow;
      int kg  = ks * 4 + kq;
      return *(const s16x8*)&Bb[row * 64 + ((kg ^ (row & 7)) * 8)];
    };

    // ---- phase 0: needs A passes {0,2}, B passes {0,2} of tile t ----
    asm volatile("s_waitcnt vmcnt(4)" ::: "memory");
    __builtin_amdgcn_s_barrier();
    asm volatile("" ::: "memory");
    if (pre) { stageA(t + 1, 0); stageA(t + 1, 2); stageB(t + 1, 0); stageB(t + 1, 2); }
    s16x8 a0[4][2], b0[2][2];
#pragma unroll
    for (int mi = 0; mi < 4; ++mi)
#pragma unroll
      for (int ks = 0; ks < 2; ++ks) a0[mi][ks] = ldA(mi, ks);
#pragma unroll
    for (int nj = 0; nj < 2; ++nj)
#pragma unroll
      for (int ks = 0; ks < 2; ++ks) b0[nj][ks] = ldB(nj, ks);
    __builtin_amdgcn_s_setprio(1);
#pragma unroll
    for (int mi = 0; mi < 4; ++mi)
#pragma unroll
      for (int nj = 0; nj < 2; ++nj) {
        acc[mi][nj] = __builtin_amdgcn_mfma_f32_16x16x32_bf16(a0[mi][0], b0[nj][0], acc[mi][nj], 0, 0, 0);
        acc[mi][nj] = __builtin_amdgcn_mfma_f32_16x16x32_bf16(a0[mi][1], b0[nj][1], acc[mi][nj], 0, 0, 0);
      }
    __builtin_amdgcn_s_setprio(0);

    // ---- phase 1: needs B passes {1,3} of tile t ----
    if (pre) asm volatile("s_waitcnt vmcnt(6)" ::: "memory");
    else     asm volatile("s_waitcnt vmcnt(2)" ::: "memory");
    __builtin_amdgcn_s_barrier();
    asm volatile("" ::: "memory");
    if (pre) { stageB(t + 1, 1); stageB(t + 1, 3); }
    s16x8 b1[2][2];
#pragma unroll
    for (int nj = 0; nj < 2; ++nj)
#pragma unroll
      for (int ks = 0; ks < 2; ++ks) b1[nj][ks] = ldB(2 + nj, ks);
    __builtin_amdgcn_s_setprio(1);
#pragma unroll
    for (int mi = 0; mi < 4; ++mi)
#pragma unroll
      for (int nj = 0; nj < 2; ++nj) {
        acc[mi][2 + nj] = __builtin_amdgcn_mfma_f32_16x16x32_bf16(a0[mi][0], b1[nj][0], acc[mi][2 + nj], 0, 0, 0);
        acc[mi][2 + nj] = __builtin_amdgcn_mfma_f32_16x16x32_bf16(a0[mi][1], b1[nj][1], acc[mi][2 + nj], 0, 0, 0);
      }
    __builtin_amdgcn_s_setprio(0);

    // ---- phase 2: needs A passes {1,3} of tile t ----
    if (pre) asm volatile("s_waitcnt vmcnt(6)" ::: "memory");
    else     asm volatile("s_waitcnt vmcnt(0)" ::: "memory");
    __builtin_amdgcn_s_barrier();
    asm volatile("" ::: "memory");
    if (pre) { stageA(t + 1, 1); stageA(t + 1, 3); }
    s16x8 a1[4][2];
#pragma unroll
    for (int mi = 0; mi < 4; ++mi)
#pragma unroll
      for (int ks = 0; ks < 2; ++ks) a1[mi][ks] = ldA(4 + mi, ks);
    __builtin_amdgcn_s_setprio(1);
#pragma unroll
    for (int mi = 0; mi < 4; ++mi)
#pragma unroll
      for (int nj = 0; nj < 2; ++nj) {
        acc[4 + mi][nj] = __builtin_amdgcn_mfma_f32_16x16x32_bf16(a1[mi][0], b0[nj][0], acc[4 + mi][nj], 0, 0, 0);
        acc[4 + mi][nj] = __builtin_amdgcn_mfma_f32_16x16x32_bf16(a1[mi][1], b0[nj][1], acc[4 + mi][nj], 0, 0, 0);
      }
#pragma unroll
    for (int mi = 0; mi < 4; ++mi)
#pragma unroll
      for (int nj = 0; nj < 2; ++nj) {
        acc[4 + mi][2 + nj] = __builtin_amdgcn_mfma_f32_16x16x32_bf16(a1[mi][0], b1[nj][0], acc[4 + mi][2 + nj], 0, 0, 0);
        acc[4 + mi][2 + nj] = __builtin_amdgcn_mfma_f32_16x16x32_bf16(a1[mi][1], b1[nj][1], acc[4 + mi][2 + nj], 0, 0, 0);
      }
    __builtin_amdgcn_s_setprio(0);
    asm volatile("" ::: "memory");
  }

  // epilogue: C/D layout col=lane&15, row=(lane>>4)*4+j (m89-verified)
#pragma unroll
  for (int mi = 0; mi < 8; ++mi) {
    int rowb = row0 + wr * 128 + mi * 16 + kq * 4;
#pragma unroll
    for (int nj = 0; nj < 4; ++nj) {
      int col = n0 + wc * 64 + nj * 16 + frow;
      float bval = bias[col];
#pragma unroll
      for (int j = 0; j < 4; ++j) {
        int rr = rowb + j;
        float v = acc[mi][nj][j] + bval;
        size_t idx = (size_t)rr * N + col;
        if (EPI == E_SIG) {
          Cb[idx] = __float2bfloat16(1.f / (1.f + __expf(-v)));
        } else if (EPI == E_BIAS) {
          Cb[idx] = __float2bfloat16(v);
        } else if (EPI == E_RELU) {
          Cb[idx] = __float2bfloat16(fmaxf(v, 0.f));
        } else if (EPI == E_OUT) {
          float gf = __bfloat162float(gate[idx]);
          float mf = (float)mask[rr];
          Cf[idx] = xres[idx] + v * gf * mf;   // in-place: xres == Cf, same idx
        } else if (EPI == E_FF2) {
          float mf = (float)mask[rr];
          Cf[idx] = xres[idx] + v * mf;        // in-place
        }
      }
    }
  }
}

// ---------------- column max over L (two stage) ----------------
__global__ void colmax_partial_k(const bf16* __restrict__ k, const bf16* __restrict__ v,
                                 float* __restrict__ pk, float* __restrict__ pv) {
  int b  = blockIdx.x >> 1;
  int d  = ((blockIdx.x & 1) << 8) + threadIdx.x;
  int lc = blockIdx.y;
  const int CH = SEQ / 16;
  size_t base = ((size_t)b * SEQ + (size_t)lc * CH) * 1536 + d;
  float mk = -1e30f, mv = -1e30f;
  for (int l = 0; l < CH; ++l) {
    mk = fmaxf(mk, __bfloat162float(k[base]));
    mv = fmaxf(mv, __bfloat162float(v[base]));
    base += 1536;
  }
  size_t pidx = ((size_t)lc * BATCH + b) * DMODEL + d;
  pk[pidx] = mk; pv[pidx] = mv;
}

__global__ void colmax_final_k(const float* __restrict__ pk, const float* __restrict__ pv,
                               float* __restrict__ kg, float* __restrict__ vg) {
  int b = blockIdx.x >> 1;
  int d = ((blockIdx.x & 1) << 8) + threadIdx.x;
  float mk = -1e30f, mv = -1e30f;
  for (int lc = 0; lc < 16; ++lc) {
    size_t pidx = ((size_t)lc * BATCH + b) * DMODEL + d;
    mk = fmaxf(mk, pk[pidx]);
    mv = fmaxf(mv, pv[pidx]);
  }
  kg[(size_t)b * DMODEL + d] = mk;
  vg[(size_t)b * DMODEL + d] = mv;
}

// ---------------- 2-way softmax attention (wave per token) ----------------
__global__ void attn_k(const bf16* __restrict__ qkv, const float* __restrict__ kg,
                       const float* __restrict__ vg, bf16* __restrict__ o) {
  int wid = threadIdx.x >> 6, lane = threadIdx.x & 63;
  int m = blockIdx.x * 4 + wid;
  int b = m >> 11;   // SEQ = 2048
  size_t base3 = (size_t)m * 1536;
  size_t baseo = (size_t)m * DMODEL;
  const float scale = 0.04419417382415922f;  // 1/sqrt(512)
#pragma unroll
  for (int h = 0; h < 8; ++h) {
    int d = (h << 6) + lane;
    float qv  = __bfloat162float(qkv[base3 + d]);
    float kv  = __bfloat162float(qkv[base3 + 512 + d]);
    float vv  = __bfloat162float(qkv[base3 + 1024 + d]);
    float kgv = kg[((size_t)b << 9) + d];
    float vgv = vg[((size_t)b << 9) + d];
    float sl = qv * kv, sg = qv * kgv;
#pragma unroll
    for (int off = 32; off; off >>= 1) {
      sl += __shfl_xor(sl, off);
      sg += __shfl_xor(sg, off);
    }
    sl *= scale; sg *= scale;
    float mx = fmaxf(sl, sg);
    float e0 = __expf(sl - mx), e1 = __expf(sg - mx);
    float inv = 1.f / (e0 + e1);
    o[baseo + d] = __float2bfloat16((e0 * vv + e1 * vgv) * inv);
  }
}

// ---------------- residual + LayerNorm (in-place on xo) ----------------
__global__ void ln_k(const float* r, const float* __restrict__ g,
                     const float* __restrict__ b, float* xo,
                     bf16* __restrict__ xb) {
  int row = blockIdx.x;
  int tid = threadIdx.x;
  size_t base = (size_t)row * DMODEL;
  float v0 = r[base + tid], v1 = r[base + tid + 256];
  float s = v0 + v1, ss = v0 * v0 + v1 * v1;
#pragma unroll
  for (int off = 32; off; off >>= 1) {
    s  += __shfl_xor(s, off);
    ss += __shfl_xor(ss, off);
  }
  __shared__ float sbuf[8];
  int w = tid >> 6, lane = tid & 63;
  if (lane == 0) { sbuf[w] = s; sbuf[4 + w] = ss; }
  __syncthreads();
  if (tid == 0) {
    float st  = sbuf[0] + sbuf[1] + sbuf[2] + sbuf[3];
    float sst = sbuf[4] + sbuf[5] + sbuf[6] + sbuf[7];
    float mean = st / (float)DMODEL;
    float var  = sst / (float)DMODEL - mean * mean;
    sbuf[0] = mean;
    sbuf[1] = rsqrtf(var + 1e-5f);
  }
  __syncthreads();
  float mean = sbuf[0], inv = sbuf[1];
  float y0 = (v0 - mean) * inv * g[tid] + b[tid];
  float y1 = (v1 - mean) * inv * g[tid + 256] + b[tid + 256];
  xo[base + tid] = y0;
  xo[base + tid + 256] = y1;
  xb[base + tid] = __float2bfloat16(y0);
  xb[base + tid + 256] = __float2bfloat16(y1);
}

// ---------------- launch ----------------
extern "C" void kernel_launch(void* const* d_in, const int* in_sizes, int n_in,
                              void* d_out, int out_size, void* d_ws, size_t ws_size,
                              hipStream_t stream) {
  (void)in_sizes; (void)n_in; (void)out_size;
  const float* x      = (const float*)d_in[0];
  const int*   xmask  = (const int*)d_in[1];
  const float* w_qkv  = (const float*)d_in[2];
  const float* b_qkv  = (const float*)d_in[3];
  const float* w_gate = (const float*)d_in[4];
  const float* b_gate = (const float*)d_in[5];
  const float* w_out  = (const float*)d_in[6];
  const float* b_out  = (const float*)d_in[7];
  const float* ln1_g  = (const float*)d_in[8];
  const float* ln1_b  = (const float*)d_in[9];
  const float* w_ff1  = (const float*)d_in[10];
  const float* b_ff1  = (const float*)d_in[11];
  const float* w_ff2  = (const float*)d_in[12];
  const float* b_ff2  = (const float*)d_in[13];
  const float* ln2_g  = (const float*)d_in[14];
  const float* ln2_b  = (const float*)d_in[15];
  float* xo = (float*)d_out;

  char* ws = (char*)d_ws;
  size_t off = 0;
  auto alloc = [&](size_t bytes) {
    char* p = ws + off;
    off += (bytes + 255) & ~(size_t)255;
    return p;
  };
  // xb: bf16 copy of x (always live)
  bf16* xb = (bf16*)alloc((size_t)MROWS * DMODEL * 2);
  // shared region: [qkvb | gateb] during attention phase, hb during FFN phase
  char* R2 = alloc((size_t)MROWS * FFDIM * 2);              // 134,217,728 B
  bf16* qkvb  = (bf16*)R2;                                  // 100,663,296 B
  bf16* gateb = (bf16*)(R2 + (size_t)MROWS * 1536 * 2);     //  33,554,432 B
  bf16* hb    = (bf16*)R2;                                  // 134,217,728 B (FFN phase)
  bf16* ob    = (bf16*)alloc((size_t)MROWS * DMODEL * 2);
  float* kg   = (float*)alloc((size_t)BATCH * DMODEL * 4);
  float* vg   = (float*)alloc((size_t)BATCH * DMODEL * 4);
  float* pk   = (float*)alloc((size_t)16 * BATCH * DMODEL * 4);
  float* pv   = (float*)alloc((size_t)16 * BATCH * DMODEL * 4);
  bf16* zbuf  = (bf16*)alloc(256);
  // per-layer repacked weights (overwritten each layer)
  bf16* wq  = (bf16*)alloc((size_t)9 * DMODEL * DMODEL * 2);
  bf16* wg  = (bf16*)alloc((size_t)DMODEL * DMODEL * 2);
  bf16* wo  = (bf16*)alloc((size_t)3 * DMODEL * DMODEL * 2);
  bf16* wf1 = (bf16*)alloc((size_t)FFDIM * DMODEL * 2);
  bf16* wf2 = (bf16*)alloc((size_t)DMODEL * FFDIM * 2);

  // tripwire: if ws is too small, do nothing -> clean absmax fail (not a crash)
  if (off > ws_size) return;

  hipMemsetAsync(zbuf, 0, 256, stream);
  x_init_k<<<2048, 256, 0, stream>>>(x, xo, xb, (size_t)MROWS * DMODEL);

  dim3 gN512(512 / 256, MROWS / 256);    // (2, 128)  -> 256 blocks
  dim3 gN1536(1536 / 256, MROWS / 256);  // (6, 128)  -> 768 blocks
  dim3 gN2048(2048 / 256, MROWS / 256);  // (8, 128)  -> 1024 blocks

  for (int i = 0; i < NLAYER; ++i) {
    // repack this layer's weights to bf16 [N][K] per tap
    cvt_k<<<1024, 256, 0, stream>>>(w_gate + (size_t)i * DMODEL * DMODEL, wg,
                                    (size_t)DMODEL * DMODEL);
    repack_qkv_layer_k<<<9216, 256, 0, stream>>>(
        w_qkv + (size_t)i * 3 * DMODEL * DMODEL * 3, wq);
    repack_out_layer_k<<<3072, 256, 0, stream>>>(
        w_out + (size_t)i * DMODEL * DMODEL * 3, wo);
    cvt_k<<<4096, 256, 0, stream>>>(w_ff1 + (size_t)i * FFDIM * DMODEL, wf1,
                                    (size_t)FFDIM * DMODEL);
    cvt_k<<<4096, 256, 0, stream>>>(w_ff2 + (size_t)i * DMODEL * FFDIM, wf2,
                                    (size_t)DMODEL * FFDIM);

    // gate = sigmoid(x @ w_gate^T + b_gate)
    gemm_k<1, E_SIG, 512><<<gN512, 512, 0, stream>>>(
        xb, wg, b_gate + (size_t)i * DMODEL, gateb, nullptr,
        nullptr, nullptr, nullptr, zbuf, MROWS, DMODEL);
    // qkv = conv1d3(x) fused over q/k/v, N = 1536
    gemm_k<3, E_BIAS, 512><<<gN1536, 512, 0, stream>>>(
        xb, wq, b_qkv + (size_t)i * 3 * DMODEL, qkvb, nullptr,
        nullptr, nullptr, nullptr, zbuf, MROWS, 1536);
    // k_g, v_g global max over L
    colmax_partial_k<<<dim3(32, 16), 256, 0, stream>>>(qkvb + 512, qkvb + 1024, pk, pv);
    colmax_final_k<<<32, 256, 0, stream>>>(pk, pv, kg, vg);
    // 2-way softmax attention
    attn_k<<<MROWS / 4, 256, 0, stream>>>(qkvb, kg, vg, ob);
    // xo = xo + conv1d3(o) * gate * mask   (in-place residual)
    gemm_k<3, E_OUT, 512><<<gN512, 512, 0, stream>>>(
        ob, wo, b_out + (size_t)i * DMODEL, nullptr, xo,
        gateb, xmask, xo, zbuf, MROWS, DMODEL);
    // x = LN(xo)  (in-place)
    ln_k<<<MROWS, 256, 0, stream>>>(xo, ln1_g + (size_t)i * DMODEL,
                                    ln1_b + (size_t)i * DMODEL, xo, xb);
    // h = relu(x @ w_ff1^T + b_ff1)
    gemm_k<1, E_RELU, 512><<<gN2048, 512, 0, stream>>>(
        xb, wf1, b_ff1 + (size_t)i * FFDIM, hb, nullptr,
        nullptr, nullptr, nullptr, zbuf, MROWS, FFDIM);
    // xo = xo + (h @ w_ff2^T + b_ff2) * mask   (in-place residual)
    gemm_k<1, E_FF2, 2048><<<gN512, 512, 0, stream>>>(
        hb, wf2, b_ff2 + (size_t)i * DMODEL, nullptr, xo,
        nullptr, xmask, xo, zbuf, MROWS, DMODEL);
    // x = LN(xo)  (in-place)
    ln_k<<<MROWS, 256, 0, stream>>>(xo, ln2_g + (size_t)i * DMODEL,
                                    ln2_b + (size_t)i * DMODEL, xo, xb);
  }
}